// Round 6
// baseline (303.162 us; speedup 1.0000x reference)
//
#include <hip/hip_runtime.h>
#include <hip/hip_bf16.h>

#define NN 100000
#define EE 1000000
#define H_DIM 124
#define PCOLS 512
#define LDK 136   // 128 + 8 bf16 pad
#define CW 132    // f32 staging stride in dwords

typedef float f32x4 __attribute__((ext_vector_type(4)));
typedef short bf16x8 __attribute__((ext_vector_type(8)));
typedef _Float16 h2 __attribute__((ext_vector_type(2)));

__device__ __forceinline__ unsigned short f2bf(float f) {
    unsigned int x = __float_as_uint(f);
    unsigned int r = (x + 0x7FFFu + ((x >> 16) & 1u)) >> 16;
    return (unsigned short)r;
}
__device__ __forceinline__ unsigned int pk2bf(float a, float b) {
    return (unsigned int)f2bf(a) | ((unsigned int)f2bf(b) << 16);
}
__device__ __forceinline__ unsigned int pk2h(float a, float b) {
    h2 v = (h2){(_Float16)a, (_Float16)b};
    return __builtin_bit_cast(unsigned int, v);
}

__device__ __forceinline__ float fdot2(h2 a, h2 b, float c) {
#if __has_builtin(__builtin_amdgcn_fdot2)
    return __builtin_amdgcn_fdot2(a, b, c, false);
#else
    return c + (float)a[0] * (float)b[0] + (float)a[1] * (float)b[1];
#endif
}

// Force a value to stay register-resident: a volatile asm result cannot be
// rematerialized or re-loaded, so the allocator must keep it live in a VGPR.
__device__ __forceinline__ h2 pin_h2(h2 x) {
    int xi = __builtin_bit_cast(int, x);
    asm volatile("" : "+v"(xi));
    return __builtin_bit_cast(h2, xi);
}

#if __has_builtin(__builtin_amdgcn_update_dpp)
template <int CTRL>
__device__ __forceinline__ float dpp_add(float x) {
    int xi = __builtin_bit_cast(int, x);
    int t = __builtin_amdgcn_update_dpp(xi, xi, CTRL, 0xF, 0xF, false);
    return x + __builtin_bit_cast(float, t);
}
__device__ __forceinline__ float reduce16(float x) {
    x = dpp_add<0x128>(x);   // row_ror:8
    x = dpp_add<0x124>(x);   // row_ror:4
    x = dpp_add<0x122>(x);   // row_ror:2
    x = dpp_add<0x121>(x);   // row_ror:1
    return x;
}
#else
__device__ __forceinline__ float reduce16(float x) {
    x += __shfl_xor(x, 8); x += __shfl_xor(x, 4);
    x += __shfl_xor(x, 2); x += __shfl_xor(x, 1);
    return x;
}
#endif

struct alignas(16) H8 { h2 p[4]; };

// ---------------- Kernel 1: W1T (bf16 [512,128]) ----------------
__global__ __launch_bounds__(256) void build_w1t(const float* __restrict__ W1,
                                                 unsigned short* __restrict__ W1T) {
    int t2 = blockIdx.x * 256 + threadIdx.x;     // 0 .. 65535
    int j = t2 >> 7, k = t2 & 127;
    int row = (j < 256) ? k : (130 + k);
    int col = (j < 256) ? j : (j - 256);
    W1T[t2] = f2bf(W1[row * 256 + col]);
}

// ---------------- Kernel 2: fused F-build + P = F @ W1cat (+b1 on dst half) -> fp16 ----------------
__global__ __launch_bounds__(256) void p_gemm(const float* __restrict__ h,
                                              const float* __restrict__ cls,
                                              const unsigned short* __restrict__ W1T,
                                              const float* __restrict__ b1,
                                              _Float16* __restrict__ P) {
    __shared__ alignas(16) unsigned short As[64 * LDK];
    __shared__ alignas(16) unsigned short Bs[128 * LDK];
    float* Cs = (float*)&Bs[0];
    const int m0 = blockIdx.x * 64;
    const int t = threadIdx.x;

    #pragma unroll
    for (int it = 0; it < 4; ++it) {
        int chunk = t + it * 256;
        int r = chunk >> 4, c8 = chunk & 15;
        int row = m0 + r;
        unsigned int w0 = 0, w1 = 0, w2 = 0, w3 = 0;
        if (row < NN) {
            if (c8 < 15) {
                const float* hp = h + (size_t)row * H_DIM + c8 * 8;
                float4 v0 = *(const float4*)(hp);
                float4 v1 = *(const float4*)(hp + 4);
                w0 = pk2bf(v0.x, v0.y); w1 = pk2bf(v0.z, v0.w);
                w2 = pk2bf(v1.x, v1.y); w3 = pk2bf(v1.z, v1.w);
            } else {
                float4 v0 = *(const float4*)(h + (size_t)row * H_DIM + 120);
                float4 c = *(const float4*)(cls + (size_t)row * 4);
                float m = fmaxf(fmaxf(c.x, c.y), fmaxf(c.z, c.w));
                float e0 = __expf(c.x - m), e1 = __expf(c.y - m);
                float e2 = __expf(c.z - m), e3 = __expf(c.w - m);
                float inv = 1.0f / (e0 + e1 + e2 + e3);
                w0 = pk2bf(v0.x, v0.y); w1 = pk2bf(v0.z, v0.w);
                w2 = pk2bf(e0 * inv, e1 * inv); w3 = pk2bf(e2 * inv, e3 * inv);
            }
        }
        *(uint4*)(&As[r * LDK + c8 * 8]) = make_uint4(w0, w1, w2, w3);
    }
    __syncthreads();

    const int wave = t >> 6, lane = t & 63;
    const int wm = wave & 1, wn = wave >> 1;
    const int lm = lane & 15, quad = lane >> 4;

    bf16x8 afrag[4][2];
    #pragma unroll
    for (int s = 0; s < 4; ++s) {
        int k0 = s * 32 + quad * 8;
        #pragma unroll
        for (int mt = 0; mt < 2; ++mt)
            afrag[s][mt] = *(const bf16x8*)(&As[(wm * 32 + mt * 16 + lm) * LDK + k0]);
    }

    for (int cchunk = 0; cchunk < 4; ++cchunk) {
        const int n0 = cchunk * 128;
        if (cchunk) __syncthreads();
        #pragma unroll
        for (int it = 0; it < 8; ++it) {
            int chunk = t + it * 256;
            int r = chunk >> 4, c = chunk & 15;
            float4 v = *(const float4*)(W1T + (n0 + r) * 128 + c * 8);
            *(float4*)(&Bs[r * LDK + c * 8]) = v;
        }
        __syncthreads();

        f32x4 acc[2][4];
        #pragma unroll
        for (int mt = 0; mt < 2; ++mt)
            #pragma unroll
            for (int nt = 0; nt < 4; ++nt)
                acc[mt][nt] = (f32x4){0.f, 0.f, 0.f, 0.f};

        #pragma unroll
        for (int s = 0; s < 4; ++s) {
            int k0 = s * 32 + quad * 8;
            bf16x8 b[4];
            #pragma unroll
            for (int nt = 0; nt < 4; ++nt)
                b[nt] = *(const bf16x8*)(&Bs[(wn * 64 + nt * 16 + lm) * LDK + k0]);
            #pragma unroll
            for (int mt = 0; mt < 2; ++mt)
                #pragma unroll
                for (int nt = 0; nt < 4; ++nt)
                    acc[mt][nt] = __builtin_amdgcn_mfma_f32_16x16x32_bf16(afrag[s][mt], b[nt], acc[mt][nt], 0, 0, 0);
        }
        __syncthreads();

        #pragma unroll
        for (int mt = 0; mt < 2; ++mt)
            #pragma unroll
            for (int nt = 0; nt < 4; ++nt) {
                int col = wn * 64 + nt * 16 + lm;
                int rb  = wm * 32 + mt * 16 + quad * 4;
                #pragma unroll
                for (int r = 0; r < 4; ++r)
                    Cs[(rb + r) * CW + col] = acc[mt][nt][r];
            }
        __syncthreads();

        #pragma unroll
        for (int it = 0; it < 4; ++it) {
            int chunk = t + it * 256;
            int r = chunk >> 4, c8 = chunk & 15;
            float4 a = *(const float4*)(Cs + r * CW + c8 * 8);
            float4 b = *(const float4*)(Cs + r * CW + c8 * 8 + 4);
            if (n0 >= 256) {   // dst half: fold b1 (wave-uniform branch)
                int cb = n0 + c8 * 8 - 256;
                float4 ba = *(const float4*)(b1 + cb);
                float4 bb = *(const float4*)(b1 + cb + 4);
                a.x += ba.x; a.y += ba.y; a.z += ba.z; a.w += ba.w;
                b.x += bb.x; b.y += bb.y; b.z += bb.z; b.w += bb.w;
            }
            uint4 o = make_uint4(pk2h(a.x, a.y), pk2h(a.z, a.w),
                                 pk2h(b.x, b.y), pk2h(b.z, b.w));
            int row = m0 + r;
            if (row < NN)
                *(uint4*)(P + (size_t)row * PCOLS + n0 + c8 * 8) = o;
        }
    }
}

// ---------------- Kernel 3: edges — 16 lanes/edge, 4 edges/wave, DPP reductions ----------------
#define K3_BLOCKS 4096
#define K3_WAVES  (K3_BLOCKS * 4)      // 16384
#define K3_STRIDE (K3_WAVES * 4)       // 65536 edges per round
#define K3_ROUNDS 16                   // 16*65536 = 1,048,576 >= EE

struct EIdx { int s, d; float q0, q1; };

__device__ __forceinline__ EIdx load_idx(int eg, const int* __restrict__ src,
                                         const int* __restrict__ dst,
                                         const float* __restrict__ polar) {
    int ec = (eg < EE) ? eg : 0;
    EIdx r;
    r.s = src[ec]; r.d = dst[ec];
    float2 q = *(const float2*)(polar + 2 * ec);
    r.q0 = q.x; r.q1 = q.y;
    return r;
}

__device__ __forceinline__ void load_p(const _Float16* __restrict__ P, const EIdx& I,
                                       int il, H8* A) {
    const _Float16* ps = P + (size_t)I.s * PCOLS + il * 16;
    A[0] = *(const H8*)(ps);
    A[1] = *(const H8*)(ps + 8);
    const _Float16* pd = P + (size_t)I.d * PCOLS + 256 + il * 16;
    A[2] = *(const H8*)(pd);
    A[3] = *(const H8*)(pd + 8);
}

__global__ __launch_bounds__(256) void edge_kernel(const _Float16* __restrict__ P,
                                                   const int* __restrict__ src,
                                                   const int* __restrict__ dst,
                                                   const float* __restrict__ polar,
                                                   const float* __restrict__ W1,
                                                   const float* __restrict__ gamma,
                                                   const float* __restrict__ beta,
                                                   const float* __restrict__ W2,
                                                   const float* __restrict__ b2,
                                                   float* __restrict__ out) {
    const int lane = threadIdx.x & 63;
    const int il   = lane & 15;                  // lane within edge group
    const int g    = lane >> 4;                  // edge group 0..3
    const int wid  = blockIdx.x * 4 + (threadIdx.x >> 6);
    const int jb   = il * 16;                    // first element of this lane

    // Packed fp16 constants: 6 arrays x 8 half2 (b1 folded into P) — pinned
    // register-resident (compiler otherwise re-loads + re-converts every round).
    h2 w0c[8], w1c[8], gc[8], bc[8], w2ac[8], w2bc[8];
    #pragma unroll
    for (int p = 0; p < 8; ++p) {
        int j = jb + 2 * p;
        float2 a0 = *(const float2*)(W1 + 128 * 256 + j);
        float2 a1 = *(const float2*)(W1 + 129 * 256 + j);
        float2 ag = *(const float2*)(gamma + j);
        float2 ae = *(const float2*)(beta + j);
        float4 w2v = *(const float4*)(W2 + 2 * j);
        w0c[p]  = pin_h2((h2){(_Float16)a0.x, (_Float16)a0.y});
        w1c[p]  = pin_h2((h2){(_Float16)a1.x, (_Float16)a1.y});
        gc[p]   = pin_h2((h2){(_Float16)ag.x, (_Float16)ag.y});
        bc[p]   = pin_h2((h2){(_Float16)ae.x, (_Float16)ae.y});
        w2ac[p] = pin_h2((h2){(_Float16)w2v.x, (_Float16)w2v.z});
        w2bc[p] = pin_h2((h2){(_Float16)w2v.y, (_Float16)w2v.w});
    }
    const float b20 = b2[0], b21 = b2[1];
    const h2 onep  = (h2){(_Float16)1.0f, (_Float16)1.0f};
    const h2 zerop = (h2){(_Float16)0.0f, (_Float16)0.0f};

    const int e0 = wid * 4 + g;

    EIdx I0 = load_idx(e0, src, dst, polar);
    H8 A[4]; load_p(P, I0, il, A);
    EIdx I1 = load_idx(e0 + K3_STRIDE, src, dst, polar);
    H8 B[4]; load_p(P, I1, il, B);

    #define EDGE_COMPUTE(Abuf, Ix, eg)                                        \
    {                                                                          \
        h2 p0 = (h2){(_Float16)(Ix).q0, (_Float16)(Ix).q0};                    \
        h2 p1 = (h2){(_Float16)(Ix).q1, (_Float16)(Ix).q1};                    \
        h2 z[8];                                                               \
        float sum = 0.f, ss = 0.f;                                             \
        _Pragma("unroll")                                                      \
        for (int p = 0; p < 8; ++p) {                                          \
            h2 pv = ((p < 4) ? (Abuf)[0].p[p] : (Abuf)[1].p[p - 4])            \
                  + ((p < 4) ? (Abuf)[2].p[p] : (Abuf)[3].p[p - 4]);           \
            h2 c = w0c[p] * p0 + w1c[p] * p1;                                  \
            z[p] = pv + c;                                                     \
            sum = fdot2(z[p], onep, sum);                                      \
            ss  = fdot2(z[p], z[p], ss);                                       \
        }                                                                      \
        sum = reduce16(sum); ss = reduce16(ss);                                \
        float mu   = sum * (1.0f / 256.0f);                                    \
        float var  = ss * (1.0f / 256.0f) - mu * mu;                           \
        float rstd = rsqrtf(var + 1e-5f);                                      \
        h2 muh = (h2){(_Float16)mu, (_Float16)mu};                             \
        h2 rsh = (h2){(_Float16)rstd, (_Float16)rstd};                         \
        float o0 = 0.f, o1 = 0.f;                                              \
        _Pragma("unroll")                                                      \
        for (int p = 0; p < 8; ++p) {                                          \
            h2 tt = (z[p] - muh) * rsh;                                        \
            h2 u = tt * gc[p] + bc[p];                                         \
            u = __builtin_elementwise_max(u, zerop);                           \
            o0 = fdot2(u, w2ac[p], o0);                                        \
            o1 = fdot2(u, w2bc[p], o1);                                        \
        }                                                                      \
        o0 = reduce16(o0); o1 = reduce16(o1);                                  \
        if (il == 0 && (eg) < EE)                                              \
            *(float2*)(out + 2 * (eg)) = make_float2(o0 + b20, o1 + b21);      \
    }

    #pragma unroll
    for (int r = 0; r < K3_ROUNDS; r += 2) {
        EDGE_COMPUTE(A, I0, e0 + r * K3_STRIDE);
        if (r + 2 < K3_ROUNDS) {
            I0 = load_idx(e0 + (r + 2) * K3_STRIDE, src, dst, polar);
            load_p(P, I0, il, A);
        }
        EDGE_COMPUTE(B, I1, e0 + (r + 1) * K3_STRIDE);
        if (r + 3 < K3_ROUNDS) {
            I1 = load_idx(e0 + (r + 3) * K3_STRIDE, src, dst, polar);
            load_p(P, I1, il, B);
        }
    }
    #undef EDGE_COMPUTE
}

extern "C" void kernel_launch(void* const* d_in, const int* in_sizes, int n_in,
                              void* d_out, int out_size, void* d_ws, size_t ws_size,
                              hipStream_t stream) {
    const float* h     = (const float*)d_in[0];
    const float* cls   = (const float*)d_in[1];
    const float* polar = (const float*)d_in[2];
    const int*   src   = (const int*)d_in[3];
    const int*   dst   = (const int*)d_in[4];
    const float* W1    = (const float*)d_in[5];
    const float* b1    = (const float*)d_in[6];
    const float* gamma = (const float*)d_in[7];
    const float* beta  = (const float*)d_in[8];
    const float* W2    = (const float*)d_in[9];
    const float* b2    = (const float*)d_in[10];
    float* out = (float*)d_out;

    char* ws = (char*)d_ws;
    _Float16*       P   = (_Float16*)ws;                      // N*512*2 = 102,400,000 B
    unsigned short* W1T = (unsigned short*)(ws + 102400000);  // 131,072 B

    build_w1t<<<256, 256, 0, stream>>>(W1, W1T);
    p_gemm<<<1563, 256, 0, stream>>>(h, cls, W1T, b1, P);
    edge_kernel<<<K3_BLOCKS, 256, 0, stream>>>(P, src, dst, polar, W1, gamma, beta, W2, b2, out);
}

// Round 7
// 286.320 us; speedup vs baseline: 1.0588x; 1.0588x over previous
//
#include <hip/hip_runtime.h>
#include <hip/hip_bf16.h>

#define NN 100000
#define EE 1000000
#define H_DIM 124
#define PCOLS 512
#define LDK 136   // 128 + 8 bf16 pad
#define CW 132    // f32 staging stride in dwords

typedef float f32x4 __attribute__((ext_vector_type(4)));
typedef short bf16x8 __attribute__((ext_vector_type(8)));
typedef _Float16 h2 __attribute__((ext_vector_type(2)));

__device__ __forceinline__ unsigned short f2bf(float f) {
    unsigned int x = __float_as_uint(f);
    unsigned int r = (x + 0x7FFFu + ((x >> 16) & 1u)) >> 16;
    return (unsigned short)r;
}
__device__ __forceinline__ unsigned int pk2bf(float a, float b) {
    return (unsigned int)f2bf(a) | ((unsigned int)f2bf(b) << 16);
}
__device__ __forceinline__ unsigned int pk2h(float a, float b) {
    h2 v = (h2){(_Float16)a, (_Float16)b};
    return __builtin_bit_cast(unsigned int, v);
}

__device__ __forceinline__ float fdot2(h2 a, h2 b, float c) {
#if __has_builtin(__builtin_amdgcn_fdot2)
    return __builtin_amdgcn_fdot2(a, b, c, false);
#else
    return c + (float)a[0] * (float)b[0] + (float)a[1] * (float)b[1];
#endif
}

#if __has_builtin(__builtin_amdgcn_update_dpp)
template <int CTRL>
__device__ __forceinline__ float dpp_add(float x) {
    int xi = __builtin_bit_cast(int, x);
    int t = __builtin_amdgcn_update_dpp(xi, xi, CTRL, 0xF, 0xF, false);
    return x + __builtin_bit_cast(float, t);
}
__device__ __forceinline__ float reduce16(float x) {
    x = dpp_add<0x128>(x);   // row_ror:8
    x = dpp_add<0x124>(x);   // row_ror:4
    x = dpp_add<0x122>(x);   // row_ror:2
    x = dpp_add<0x121>(x);   // row_ror:1
    return x;
}
#else
__device__ __forceinline__ float reduce16(float x) {
    x += __shfl_xor(x, 8); x += __shfl_xor(x, 4);
    x += __shfl_xor(x, 2); x += __shfl_xor(x, 1);
    return x;
}
#endif

struct alignas(16) H8 { h2 p[4]; };

// ---------------- Kernel 1: W1T (bf16 [512,128]) + packed constant table ----------------
// CT layout: lane il in [0,16) owns cols il*16..il*16+15. For each of 6 arrays
// (W1polar0, W1polar1, gamma, beta, W2a, W2b) two uint4s (8 fp16 each), order
// CT[il*12 + a*2 + k]. Total 192 uint4 = 3 KB.
__global__ __launch_bounds__(256) void build_w1t_ct(const float* __restrict__ W1,
                                                    const float* __restrict__ gamma,
                                                    const float* __restrict__ beta,
                                                    const float* __restrict__ W2,
                                                    unsigned short* __restrict__ W1T,
                                                    uint4* __restrict__ CT) {
    if (blockIdx.x < 256) {
        int t2 = blockIdx.x * 256 + threadIdx.x;     // 0 .. 65535
        int j = t2 >> 7, k = t2 & 127;
        int row = (j < 256) ? k : (130 + k);
        int col = (j < 256) ? j : (j - 256);
        W1T[t2] = f2bf(W1[row * 256 + col]);
    } else {
        int t = threadIdx.x;
        if (t < 192) {
            int slot = t % 12, il = t / 12;
            int a = slot >> 1, k = slot & 1;
            int j0 = il * 16 + k * 8;
            float v[8];
            #pragma unroll
            for (int i = 0; i < 8; ++i) {
                int j = j0 + i;
                v[i] = (a == 0) ? W1[128 * 256 + j]
                     : (a == 1) ? W1[129 * 256 + j]
                     : (a == 2) ? gamma[j]
                     : (a == 3) ? beta[j]
                     : (a == 4) ? W2[2 * j]
                     :            W2[2 * j + 1];
            }
            CT[t] = make_uint4(pk2h(v[0], v[1]), pk2h(v[2], v[3]),
                               pk2h(v[4], v[5]), pk2h(v[6], v[7]));
        }
    }
}

// ---------------- Kernel 2: fused F-build + P = F @ W1cat (+b1 on dst half) -> fp16 ----------------
__global__ __launch_bounds__(256) void p_gemm(const float* __restrict__ h,
                                              const float* __restrict__ cls,
                                              const unsigned short* __restrict__ W1T,
                                              const float* __restrict__ b1,
                                              _Float16* __restrict__ P) {
    __shared__ alignas(16) unsigned short As[64 * LDK];
    __shared__ alignas(16) unsigned short Bs[128 * LDK];
    float* Cs = (float*)&Bs[0];
    const int m0 = blockIdx.x * 64;
    const int t = threadIdx.x;

    #pragma unroll
    for (int it = 0; it < 4; ++it) {
        int chunk = t + it * 256;
        int r = chunk >> 4, c8 = chunk & 15;
        int row = m0 + r;
        unsigned int w0 = 0, w1 = 0, w2 = 0, w3 = 0;
        if (row < NN) {
            if (c8 < 15) {
                const float* hp = h + (size_t)row * H_DIM + c8 * 8;
                float4 v0 = *(const float4*)(hp);
                float4 v1 = *(const float4*)(hp + 4);
                w0 = pk2bf(v0.x, v0.y); w1 = pk2bf(v0.z, v0.w);
                w2 = pk2bf(v1.x, v1.y); w3 = pk2bf(v1.z, v1.w);
            } else {
                float4 v0 = *(const float4*)(h + (size_t)row * H_DIM + 120);
                float4 c = *(const float4*)(cls + (size_t)row * 4);
                float m = fmaxf(fmaxf(c.x, c.y), fmaxf(c.z, c.w));
                float e0 = __expf(c.x - m), e1 = __expf(c.y - m);
                float e2 = __expf(c.z - m), e3 = __expf(c.w - m);
                float inv = 1.0f / (e0 + e1 + e2 + e3);
                w0 = pk2bf(v0.x, v0.y); w1 = pk2bf(v0.z, v0.w);
                w2 = pk2bf(e0 * inv, e1 * inv); w3 = pk2bf(e2 * inv, e3 * inv);
            }
        }
        *(uint4*)(&As[r * LDK + c8 * 8]) = make_uint4(w0, w1, w2, w3);
    }
    __syncthreads();

    const int wave = t >> 6, lane = t & 63;
    const int wm = wave & 1, wn = wave >> 1;
    const int lm = lane & 15, quad = lane >> 4;

    bf16x8 afrag[4][2];
    #pragma unroll
    for (int s = 0; s < 4; ++s) {
        int k0 = s * 32 + quad * 8;
        #pragma unroll
        for (int mt = 0; mt < 2; ++mt)
            afrag[s][mt] = *(const bf16x8*)(&As[(wm * 32 + mt * 16 + lm) * LDK + k0]);
    }

    for (int cchunk = 0; cchunk < 4; ++cchunk) {
        const int n0 = cchunk * 128;
        if (cchunk) __syncthreads();
        #pragma unroll
        for (int it = 0; it < 8; ++it) {
            int chunk = t + it * 256;
            int r = chunk >> 4, c = chunk & 15;
            float4 v = *(const float4*)(W1T + (n0 + r) * 128 + c * 8);
            *(float4*)(&Bs[r * LDK + c * 8]) = v;
        }
        __syncthreads();

        f32x4 acc[2][4];
        #pragma unroll
        for (int mt = 0; mt < 2; ++mt)
            #pragma unroll
            for (int nt = 0; nt < 4; ++nt)
                acc[mt][nt] = (f32x4){0.f, 0.f, 0.f, 0.f};

        #pragma unroll
        for (int s = 0; s < 4; ++s) {
            int k0 = s * 32 + quad * 8;
            bf16x8 b[4];
            #pragma unroll
            for (int nt = 0; nt < 4; ++nt)
                b[nt] = *(const bf16x8*)(&Bs[(wn * 64 + nt * 16 + lm) * LDK + k0]);
            #pragma unroll
            for (int mt = 0; mt < 2; ++mt)
                #pragma unroll
                for (int nt = 0; nt < 4; ++nt)
                    acc[mt][nt] = __builtin_amdgcn_mfma_f32_16x16x32_bf16(afrag[s][mt], b[nt], acc[mt][nt], 0, 0, 0);
        }
        __syncthreads();

        #pragma unroll
        for (int mt = 0; mt < 2; ++mt)
            #pragma unroll
            for (int nt = 0; nt < 4; ++nt) {
                int col = wn * 64 + nt * 16 + lm;
                int rb  = wm * 32 + mt * 16 + quad * 4;
                #pragma unroll
                for (int r = 0; r < 4; ++r)
                    Cs[(rb + r) * CW + col] = acc[mt][nt][r];
            }
        __syncthreads();

        #pragma unroll
        for (int it = 0; it < 4; ++it) {
            int chunk = t + it * 256;
            int r = chunk >> 4, c8 = chunk & 15;
            float4 a = *(const float4*)(Cs + r * CW + c8 * 8);
            float4 b = *(const float4*)(Cs + r * CW + c8 * 8 + 4);
            if (n0 >= 256) {   // dst half: fold b1 (wave-uniform branch)
                int cb = n0 + c8 * 8 - 256;
                float4 ba = *(const float4*)(b1 + cb);
                float4 bb = *(const float4*)(b1 + cb + 4);
                a.x += ba.x; a.y += ba.y; a.z += ba.z; a.w += ba.w;
                b.x += bb.x; b.y += bb.y; b.z += bb.z; b.w += bb.w;
            }
            uint4 o = make_uint4(pk2h(a.x, a.y), pk2h(a.z, a.w),
                                 pk2h(b.x, b.y), pk2h(b.z, b.w));
            int row = m0 + r;
            if (row < NN)
                *(uint4*)(P + (size_t)row * PCOLS + n0 + c8 * 8) = o;
        }
    }
}

// ---------------- Kernel 3: edges — 16 lanes/edge, 4 edges/wave, depth-3 pipeline ----------------
#define K3_BLOCKS 4096
#define K3_WAVES  (K3_BLOCKS * 4)      // 16384
#define K3_STRIDE (K3_WAVES * 4)       // 65536 edges per round
#define K3_ROUNDS 16                   // 16*65536 = 1,048,576 >= EE

struct EIdx { int s, d; float q0, q1; };

__device__ __forceinline__ EIdx load_idx(int eg, const int* __restrict__ src,
                                         const int* __restrict__ dst,
                                         const float* __restrict__ polar) {
    int ec = (eg < EE) ? eg : 0;
    EIdx r;
    r.s = src[ec]; r.d = dst[ec];
    float2 q = *(const float2*)(polar + 2 * ec);
    r.q0 = q.x; r.q1 = q.y;
    return r;
}

__device__ __forceinline__ void load_p(const _Float16* __restrict__ P, const EIdx& I,
                                       int il, H8* A) {
    const _Float16* ps = P + (size_t)I.s * PCOLS + il * 16;
    A[0] = *(const H8*)(ps);
    A[1] = *(const H8*)(ps + 8);
    const _Float16* pd = P + (size_t)I.d * PCOLS + 256 + il * 16;
    A[2] = *(const H8*)(pd);
    A[3] = *(const H8*)(pd + 8);
}

__global__ __launch_bounds__(256) void edge_kernel(const _Float16* __restrict__ P,
                                                   const int* __restrict__ src,
                                                   const int* __restrict__ dst,
                                                   const float* __restrict__ polar,
                                                   const uint4* __restrict__ CT,
                                                   const float* __restrict__ b2,
                                                   float* __restrict__ out) {
    const int lane = threadIdx.x & 63;
    const int il   = lane & 15;                  // lane within edge group
    const int g    = lane >> 4;                  // edge group 0..3
    const int wid  = blockIdx.x * 4 + (threadIdx.x >> 6);

    // Pre-packed fp16 constants: 12 x dwordx4, zero conversion cost even if
    // the allocator decides to reload them per round (L1-hot 3 KB table).
    uint4 cq[12];
    #pragma unroll
    for (int i = 0; i < 12; ++i) cq[i] = CT[il * 12 + i];
    h2 w0c[8], w1c[8], gc[8], bc[8], w2ac[8], w2bc[8];
    {
        const h2* ch = (const h2*)cq;
        #pragma unroll
        for (int p = 0; p < 8; ++p) {
            w0c[p]  = ch[p];      w1c[p]  = ch[8 + p];
            gc[p]   = ch[16 + p]; bc[p]   = ch[24 + p];
            w2ac[p] = ch[32 + p]; w2bc[p] = ch[40 + p];
        }
    }
    const float b20 = b2[0], b21 = b2[1];
    const h2 onep  = (h2){(_Float16)1.0f, (_Float16)1.0f};
    const h2 zerop = (h2){(_Float16)0.0f, (_Float16)0.0f};

    const int e0 = wid * 4 + g;

    // depth-3 software pipeline, fully unrolled (SSA renaming, no rotation movs)
    EIdx I[3];
    H8 buf[3][4];
    #pragma unroll
    for (int i = 0; i < 3; ++i) {
        I[i] = load_idx(e0 + i * K3_STRIDE, src, dst, polar);
        load_p(P, I[i], il, buf[i]);
    }

    #define EDGE_COMPUTE(Abuf, Ix, eg)                                        \
    {                                                                          \
        h2 p0 = (h2){(_Float16)(Ix).q0, (_Float16)(Ix).q0};                    \
        h2 p1 = (h2){(_Float16)(Ix).q1, (_Float16)(Ix).q1};                    \
        h2 z[8];                                                               \
        float sum = 0.f, ss = 0.f;                                             \
        _Pragma("unroll")                                                      \
        for (int p = 0; p < 8; ++p) {                                          \
            h2 pv = ((p < 4) ? (Abuf)[0].p[p] : (Abuf)[1].p[p - 4])            \
                  + ((p < 4) ? (Abuf)[2].p[p] : (Abuf)[3].p[p - 4]);           \
            h2 c = w0c[p] * p0 + w1c[p] * p1;                                  \
            z[p] = pv + c;                                                     \
            sum = fdot2(z[p], onep, sum);                                      \
            ss  = fdot2(z[p], z[p], ss);                                       \
        }                                                                      \
        sum = reduce16(sum); ss = reduce16(ss);                                \
        float mu   = sum * (1.0f / 256.0f);                                    \
        float var  = ss * (1.0f / 256.0f) - mu * mu;                           \
        float rstd = rsqrtf(var + 1e-5f);                                      \
        float nmur = -mu * rstd;                                               \
        h2 rsh  = (h2){(_Float16)rstd, (_Float16)rstd};                        \
        h2 nmh  = (h2){(_Float16)nmur, (_Float16)nmur};                        \
        float o0 = 0.f, o1 = 0.f;                                              \
        _Pragma("unroll")                                                      \
        for (int p = 0; p < 8; ++p) {                                          \
            h2 tt = z[p] * rsh + nmh;                                          \
            h2 u = tt * gc[p] + bc[p];                                         \
            u = __builtin_elementwise_max(u, zerop);                           \
            o0 = fdot2(u, w2ac[p], o0);                                        \
            o1 = fdot2(u, w2bc[p], o1);                                        \
        }                                                                      \
        o0 = reduce16(o0); o1 = reduce16(o1);                                  \
        if (il == 0 && (eg) < EE)                                              \
            *(float2*)(out + 2 * (eg)) = make_float2(o0 + b20, o1 + b21);      \
    }

    #pragma unroll
    for (int r = 0; r < K3_ROUNDS; ++r) {
        const int br = r % 3;
        EDGE_COMPUTE(buf[br], I[br], e0 + r * K3_STRIDE);
        if (r + 3 < K3_ROUNDS) {
            I[br] = load_idx(e0 + (r + 3) * K3_STRIDE, src, dst, polar);
            load_p(P, I[br], il, buf[br]);
        }
    }
    #undef EDGE_COMPUTE
}

extern "C" void kernel_launch(void* const* d_in, const int* in_sizes, int n_in,
                              void* d_out, int out_size, void* d_ws, size_t ws_size,
                              hipStream_t stream) {
    const float* h     = (const float*)d_in[0];
    const float* cls   = (const float*)d_in[1];
    const float* polar = (const float*)d_in[2];
    const int*   src   = (const int*)d_in[3];
    const int*   dst   = (const int*)d_in[4];
    const float* W1    = (const float*)d_in[5];
    const float* b1    = (const float*)d_in[6];
    const float* gamma = (const float*)d_in[7];
    const float* beta  = (const float*)d_in[8];
    const float* W2    = (const float*)d_in[9];
    const float* b2    = (const float*)d_in[10];
    float* out = (float*)d_out;

    char* ws = (char*)d_ws;
    _Float16*       P   = (_Float16*)ws;                      // N*512*2 = 102,400,000 B
    unsigned short* W1T = (unsigned short*)(ws + 102400000);  // 131,072 B
    uint4*          CT  = (uint4*)(ws + 102531072);           // 3,072 B

    build_w1t_ct<<<257, 256, 0, stream>>>(W1, gamma, beta, W2, W1T, CT);
    p_gemm<<<1563, 256, 0, stream>>>(h, cls, W1T, b1, P);
    edge_kernel<<<K3_BLOCKS, 256, 0, stream>>>(P, src, dst, polar, CT, b2, out);
}